// Round 5
// baseline (508.135 us; speedup 1.0000x reference)
//
#include <hip/hip_runtime.h>

typedef unsigned short u16;
typedef unsigned int u32;
typedef __attribute__((ext_vector_type(8))) short short8;
typedef __attribute__((ext_vector_type(4))) float f32x4;

// ---------------- helpers ----------------
__device__ __forceinline__ u16 f2bf(float f) {
    unsigned int u = __float_as_uint(f);
    u += 0x7fffu + ((u >> 16) & 1u);   // round-to-nearest-even
    return (u16)(u >> 16);
}

__device__ __forceinline__ u32 pack_trunc(float a, float b) {
    return __builtin_amdgcn_perm(__float_as_uint(b), __float_as_uint(a), 0x07060302u);
}

// async global->LDS, 16B per lane. LDS dest = wave-uniform base + lane*16.
__device__ __forceinline__ void gload16(const u16* g, const u16* l) {
    __builtin_amdgcn_global_load_lds(
        (const __attribute__((address_space(1))) unsigned int*)g,
        (__attribute__((address_space(3))) unsigned int*)l, 16, 0, 0);
}

// ---------------- fused cast fp32 -> bf16 (all 7 tensors, one launch) ----------------
__global__ __launch_bounds__(256) void cast_all(const float* __restrict__ k,
                                                const float* __restrict__ q,
                                                const float* __restrict__ v,
                                                const float* __restrict__ wk,
                                                const float* __restrict__ wq,
                                                const float* __restrict__ wv,
                                                const float* __restrict__ wo,
                                                u16* __restrict__ Xk, u16* __restrict__ Xq,
                                                u16* __restrict__ Xv, u16* __restrict__ Wk,
                                                u16* __restrict__ Wq, u16* __restrict__ Wv,
                                                u16* __restrict__ Wo) {
    size_t i = ((size_t)blockIdx.x * 256 + threadIdx.x) * 8;
    const float* src; u16* dst; size_t off;
    if (i < 25165824) {                       // 3 x 2^23 activations
        int r = (int)(i >> 23); off = i & 8388607;
        src = r == 0 ? k : (r == 1 ? q : v);
        dst = r == 0 ? Xk : (r == 1 ? Xq : Xv);
    } else {                                  // 4 x 2^20 weights
        size_t j = i - 25165824;
        int r = (int)(j >> 20); off = j & 1048575;
        src = r == 0 ? wk : (r == 1 ? wq : (r == 2 ? wv : wo));
        dst = r == 0 ? Wk : (r == 1 ? Wq : (r == 2 ? Wv : Wo));
    }
    float4 a = *(const float4*)(src + off);
    float4 b = *(const float4*)(src + off + 4);
    union { u16 h[8]; uint4 u; } r8;
    r8.h[0] = f2bf(a.x); r8.h[1] = f2bf(a.y); r8.h[2] = f2bf(a.z); r8.h[3] = f2bf(a.w);
    r8.h[4] = f2bf(b.x); r8.h[5] = f2bf(b.y); r8.h[6] = f2bf(b.z); r8.h[7] = f2bf(b.w);
    *(uint4*)(dst + off) = r8.u;
}

// =====================================================================================
// GEMM core (R4, verified): 2-phase structure, BK=64, 128x128 tile, 4 waves.
// Bank swizzle: LDS row = 128B = 8 x 16B slots; LDS[r][slot] holds global[r][slot^(r&7)],
// staged by pre-permuting the global SOURCE column; reads use slot (kh*4+quad)^(l16&7).
// =====================================================================================

// ---------------- batched QKV GEMM, XCD-swizzled 1-D grid (1536 blocks) ----------------
__global__ __launch_bounds__(256) void gemm_qkv(const u16* __restrict__ Xk,
                                                const u16* __restrict__ Xq,
                                                const u16* __restrict__ Xv,
                                                const u16* __restrict__ Wk,
                                                const u16* __restrict__ Wq,
                                                const u16* __restrict__ Wv,
                                                const float* __restrict__ bK,
                                                const float* __restrict__ bQ,
                                                const float* __restrict__ bV,
                                                u16* __restrict__ Kbh,
                                                u16* __restrict__ Qbh,
                                                u16* __restrict__ Vtg,
                                                float kscale) {
    __shared__ u16 sA[128 * 64];
    __shared__ u16 sB[128 * 64];
    const int f = blockIdx.x;
    const int z = f >> 9;
    const int r9 = f & 511;
    const int i_idx = (r9 & 7) | (((r9 >> 6) & 7) << 3);
    const int j_idx = (r9 >> 3) & 7;

    const u16* X = z == 0 ? Xk : (z == 1 ? Xq : Xv);
    const u16* W = z == 0 ? Wk : (z == 1 ? Wq : Wv);
    const float* bias = z == 0 ? bK : (z == 1 ? bQ : bV);
    u16* out = z == 0 ? Kbh : (z == 1 ? Qbh : Vtg);
    const float scale = z == 0 ? kscale : 1.0f;

    const int tid  = threadIdx.x;
    const int wave = tid >> 6, lane = tid & 63;
    const int quad = lane >> 4, l16 = lane & 15;
    const int wm = wave & 1, wn = wave >> 1;
    const int i0 = i_idx * 128, j0 = j_idx * 128;

    const int r = tid >> 3;
    const int sg = (tid & 7) ^ (r & 7);
    const u16* gA = X + (size_t)(i0 + r) * 1024 + sg * 8;
    const u16* gB = W + (size_t)(j0 + r) * 1024 + sg * 8;
    u16* dA = sA + wave * 512;
    u16* dB = sB + wave * 512;
    const int sx = l16 & 7;   // read-side XOR

    f32x4 acc[4][4];
    #pragma unroll
    for (int mt = 0; mt < 4; mt++)
        #pragma unroll
        for (int nt = 0; nt < 4; nt++) acc[mt][nt] = (f32x4){0.f, 0.f, 0.f, 0.f};

    for (int kk = 0; kk < 1024; kk += 64) {
        __syncthreads();
        gload16(gA + kk,         dA);
        gload16(gA + kk + 32768, dA + 2048);
        gload16(gA + kk + 65536, dA + 4096);
        gload16(gA + kk + 98304, dA + 6144);
        gload16(gB + kk,         dB);
        gload16(gB + kk + 32768, dB + 2048);
        gload16(gB + kk + 65536, dB + 4096);
        gload16(gB + kk + 98304, dB + 6144);
        __syncthreads();
        short8 bf[4][2];
        #pragma unroll
        for (int nt = 0; nt < 4; nt++)
            #pragma unroll
            for (int kh = 0; kh < 2; kh++)
                bf[nt][kh] = *(const short8*)&sB[(wn * 64 + nt * 16 + l16) * 64 +
                                                 ((kh * 4 + quad) ^ sx) * 8];
        #pragma unroll
        for (int mt = 0; mt < 4; mt++) {
            const int arow = (wm * 64 + mt * 16 + l16) * 64;
            short8 a0 = *(const short8*)&sA[arow + ((quad) ^ sx) * 8];
            short8 a1 = *(const short8*)&sA[arow + ((4 + quad) ^ sx) * 8];
            #pragma unroll
            for (int nt = 0; nt < 4; nt++) {
                acc[mt][nt] = __builtin_amdgcn_mfma_f32_16x16x32_bf16(a0, bf[nt][0], acc[mt][nt], 0, 0, 0);
                acc[mt][nt] = __builtin_amdgcn_mfma_f32_16x16x32_bf16(a1, bf[nt][1], acc[mt][nt], 0, 0, 0);
            }
        }
    }

    #pragma unroll
    for (int mt = 0; mt < 4; mt++) {
        #pragma unroll
        for (int nt = 0; nt < 4; nt++) {
            int j = j0 + wn * 64 + nt * 16 + l16;
            float bj = bias[j];
            #pragma unroll
            for (int rr = 0; rr < 4; rr++) {
                int i = i0 + wm * 64 + mt * 16 + quad * 4 + rr;
                float v = (acc[mt][nt][rr] + bj) * scale;
                int b = i >> 11, t = i & 2047;
                int h = j >> 6,  dd = j & 63;
                size_t idx;
                if (z == 2) idx = (((size_t)(b * 16 + h)) * 64 + dd) * 2048 + t;
                else        idx = (((size_t)(b * 16 + h)) * 2048 + t) * 64 + dd;
                out[idx] = f2bf(v);
            }
        }
    }
}

// ---------------- output GEMM: 128x64 tile, XCD-swizzled (1024 blocks), BK=64 ---------
__global__ __launch_bounds__(256) void gemm_out(const u16* __restrict__ X,
                                                const u16* __restrict__ W,
                                                const float* __restrict__ bias,
                                                float* __restrict__ out) {
    __shared__ u16 sA[128 * 64];
    __shared__ u16 sB[64 * 64];
    const int f = blockIdx.x;
    const int j_idx = (f >> 3) & 15;
    const int i_idx = (f & 7) | ((f >> 7) << 3);
    const int tid  = threadIdx.x;
    const int wave = tid >> 6, lane = tid & 63;
    const int quad = lane >> 4, l16 = lane & 15;
    const int wm = wave & 1, wn = wave >> 1;
    const int i0 = i_idx * 128, j0 = j_idx * 64;

    const int r = tid >> 3;
    const int sg = (tid & 7) ^ (r & 7);
    const u16* gA = X + (size_t)(i0 + r) * 1024 + sg * 8;
    const u16* gB = W + (size_t)(j0 + r) * 1024 + sg * 8;
    u16* dA = sA + wave * 512;
    u16* dB = sB + wave * 512;
    const int sx = l16 & 7;

    f32x4 acc[4][2];
    #pragma unroll
    for (int mt = 0; mt < 4; mt++) {
        acc[mt][0] = (f32x4){0.f, 0.f, 0.f, 0.f};
        acc[mt][1] = (f32x4){0.f, 0.f, 0.f, 0.f};
    }

    for (int kk = 0; kk < 1024; kk += 64) {
        __syncthreads();
        gload16(gA + kk,         dA);
        gload16(gA + kk + 32768, dA + 2048);
        gload16(gA + kk + 65536, dA + 4096);
        gload16(gA + kk + 98304, dA + 6144);
        gload16(gB + kk,         dB);
        gload16(gB + kk + 32768, dB + 2048);
        __syncthreads();
        short8 bf[2][2];
        #pragma unroll
        for (int nt = 0; nt < 2; nt++)
            #pragma unroll
            for (int kh = 0; kh < 2; kh++)
                bf[nt][kh] = *(const short8*)&sB[(wn * 32 + nt * 16 + l16) * 64 +
                                                 ((kh * 4 + quad) ^ sx) * 8];
        #pragma unroll
        for (int mt = 0; mt < 4; mt++) {
            const int arow = (wm * 64 + mt * 16 + l16) * 64;
            short8 a0 = *(const short8*)&sA[arow + ((quad) ^ sx) * 8];
            short8 a1 = *(const short8*)&sA[arow + ((4 + quad) ^ sx) * 8];
            #pragma unroll
            for (int nt = 0; nt < 2; nt++) {
                acc[mt][nt] = __builtin_amdgcn_mfma_f32_16x16x32_bf16(a0, bf[nt][0], acc[mt][nt], 0, 0, 0);
                acc[mt][nt] = __builtin_amdgcn_mfma_f32_16x16x32_bf16(a1, bf[nt][1], acc[mt][nt], 0, 0, 0);
            }
        }
    }

    #pragma unroll
    for (int mt = 0; mt < 4; mt++) {
        #pragma unroll
        for (int nt = 0; nt < 2; nt++) {
            int j = j0 + wn * 32 + nt * 16 + l16;
            float bj = bias[j];
            #pragma unroll
            for (int rr = 0; rr < 4; rr++) {
                int i = i0 + wm * 64 + mt * 16 + quad * 4 + rr;
                out[(size_t)i * 1024 + j] = acc[mt][nt][rr] + bj;
            }
        }
    }
}

// ---------------- flash attention v5 (1024 blocks, 4 blocks/CU) ----------------
// Changes vs v4: (a) LDS relayout to 128B rows + 16B-slot XOR swizzle (the pattern that
// measured ZERO conflicts in the GEMMs; QST=72 measured 10.5M); (b) T-chunks 8->16 so
// per-wave state halves (bk[2][2], accO[2][4]) -> VGPR fits 4 blocks/CU at 32KB LDS;
// (c) s_setprio(1) around MFMA clusters (m191: +4-7% on attn).
// XCD swizzle: XCD = f&7; tx = (f>>3)&15; bh = (f&7) | ((f>>7)<<3). All 16 tx-blocks of
// a head share one XCD -> Q/K/V of that head stay in its L2.
__global__ __launch_bounds__(256, 4) void attn_kernel(const u16* __restrict__ Kbh,
                                                      const u16* __restrict__ Qbh,
                                                      const u16* __restrict__ Vtg,
                                                      u16* __restrict__ ctx) {
    __shared__ u16 sQ[64 * 64];              // [s_local][dk], swizzled slots
    __shared__ u16 sVt[64 * 64];             // [dk][s_local], swizzled slots
    __shared__ u16 sP[4 * 2 * 16 * 64];      // [wave][buf][t16][s64], swizzled 8B units
    const int f = blockIdx.x;
    const int bh = (f & 7) | ((f >> 7) << 3);
    const int tx = (f >> 3) & 15;
    const int tid  = threadIdx.x;
    const int wave = tid >> 6, lane = tid & 63;
    const int quad = lane >> 4, l16 = lane & 15;
    const int sx = l16 & 7;
    const int tw = tx * 128 + wave * 32;
    const size_t base = (size_t)bh * 2048 * 64;

    // K as B-fragments, 2 t-groups x 2 dk-chunks, held in regs
    short8 bk[2][2];
    #pragma unroll
    for (int g = 0; g < 2; g++) {
        const u16* kr = Kbh + base + (size_t)(tw + g * 16 + l16) * 64 + quad * 8;
        bk[g][0] = *(const short8*)kr;
        bk[g][1] = *(const short8*)(kr + 32);
    }
    const short8 ones = {0x3F80, 0x3F80, 0x3F80, 0x3F80, 0x3F80, 0x3F80, 0x3F80, 0x3F80};

    f32x4 accO[2][4];
    #pragma unroll
    for (int g = 0; g < 2; g++)
        #pragma unroll
        for (int dt = 0; dt < 4; dt++) accO[g][dt] = (f32x4){0.f, 0.f, 0.f, 0.f};
    f32x4 accL[2];
    accL[0] = (f32x4){0.f, 0.f, 0.f, 0.f};
    accL[1] = (f32x4){0.f, 0.f, 0.f, 0.f};

    const int srow = tid >> 2, seg = tid & 3;
    const int s7 = srow & 7;
    const int st0 = ((2 * seg)     ^ s7) * 8;   // swizzled 16B-slot offsets for staging
    const int st1 = ((2 * seg + 1) ^ s7) * 8;
    u16* sPw = sP + wave * 2048;

    for (int s0 = 0; s0 < 2048; s0 += 64) {
        __syncthreads();
        {   // stage Q chunk [s][dk], swizzled
            const uint4* gq = (const uint4*)(Qbh + base + (size_t)(s0 + srow) * 64 + seg * 16);
            uint4 q0 = gq[0], q1 = gq[1];
            *(uint4*)&sQ[srow * 64 + st0] = q0;
            *(uint4*)&sQ[srow * 64 + st1] = q1;
        }
        {   // stage V^T chunk [dk][s], swizzled
            const uint4* gv = (const uint4*)(Vtg + ((size_t)bh * 64 + srow) * 2048 + s0 + seg * 16);
            uint4 v0 = gv[0], v1 = gv[1];
            *(uint4*)&sVt[srow * 64 + st0] = v0;
            *(uint4*)&sVt[srow * 64 + st1] = v1;
        }
        __syncthreads();

        // cache Q A-frags and V^T A-frags once; reuse for both t-groups
        short8 aq[4][2], av[2][4];
        #pragma unroll
        for (int nt = 0; nt < 4; nt++)
            #pragma unroll
            for (int kh = 0; kh < 2; kh++)
                aq[nt][kh] = *(const short8*)&sQ[(nt * 16 + l16) * 64 +
                                                 ((kh * 4 + quad) ^ sx) * 8];
        #pragma unroll
        for (int kk = 0; kk < 2; kk++)
            #pragma unroll
            for (int dt = 0; dt < 4; dt++)
                av[kk][dt] = *(const short8*)&sVt[(dt * 16 + l16) * 64 +
                                                  ((kk * 4 + quad) ^ sx) * 8];

        #pragma unroll
        for (int g = 0; g < 2; g++) {
            // S^T[s][t] for this group: A = Q (cached), B = K (regs)
            f32x4 aS[4];
            __builtin_amdgcn_s_setprio(1);
            #pragma unroll
            for (int nt = 0; nt < 4; nt++) {
                f32x4 s = __builtin_amdgcn_mfma_f32_16x16x32_bf16(aq[nt][0], bk[g][0],
                            (f32x4){0.f, 0.f, 0.f, 0.f}, 0, 0, 0);
                aS[nt] = __builtin_amdgcn_mfma_f32_16x16x32_bf16(aq[nt][1], bk[g][1], s, 0, 0, 0);
            }
            __builtin_amdgcn_s_setprio(0);
            // P^T = 2^(S^T): raw v_exp_f32, truncate-pack to bf16, swizzled 8B units
            u16* pb = sPw + (g & 1) * 1024;
            #pragma unroll
            for (int nt = 0; nt < 4; nt++) {
                float p0 = __builtin_amdgcn_exp2f(aS[nt][0]);
                float p1 = __builtin_amdgcn_exp2f(aS[nt][1]);
                float p2 = __builtin_amdgcn_exp2f(aS[nt][2]);
                float p3 = __builtin_amdgcn_exp2f(aS[nt][3]);
                uint2 pk = { pack_trunc(p0, p1), pack_trunc(p2, p3) };
                *(uint2*)&pb[l16 * 64 + ((nt * 4 + quad) ^ (sx << 1)) * 4] = pk;
            }
            // O^T += V^T @ P^T ; L += ones @ P^T
            __builtin_amdgcn_s_setprio(1);
            #pragma unroll
            for (int kk = 0; kk < 2; kk++) {
                short8 bp = *(const short8*)&pb[l16 * 64 +
                                                ((kk * 8 + quad * 2) ^ (sx << 1)) * 4];
                accL[g] = __builtin_amdgcn_mfma_f32_16x16x32_bf16(ones, bp, accL[g], 0, 0, 0);
                #pragma unroll
                for (int dt = 0; dt < 4; dt++)
                    accO[g][dt] = __builtin_amdgcn_mfma_f32_16x16x32_bf16(av[kk][dt], bp, accO[g][dt], 0, 0, 0);
            }
            __builtin_amdgcn_s_setprio(0);
        }
    }

    // epilogue: lane holds col t = tw+g*16+l16, rows d = dt*16+quad*4+r
    const int b = bh >> 4, h = bh & 15;
    #pragma unroll
    for (int g = 0; g < 2; g++) {
        float inv = 1.f / accL[g][0];
        int t = tw + g * 16 + l16;
        u16* orow = ctx + ((size_t)(b * 2048 + t)) * 1024 + h * 64;
        #pragma unroll
        for (int dt = 0; dt < 4; dt++) {
            union { u16 h4[4]; uint2 u; } o;
            #pragma unroll
            for (int rr = 0; rr < 4; rr++) o.h4[rr] = f2bf(accO[g][dt][rr] * inv);
            *(uint2*)&orow[dt * 16 + quad * 4] = o.u;
        }
    }
}

// ---------------- launcher ----------------
extern "C" void kernel_launch(void* const* d_in, const int* in_sizes, int n_in,
                              void* d_out, int out_size, void* d_ws, size_t ws_size,
                              hipStream_t stream) {
    const float* keys    = (const float*)d_in[0];
    const float* queries = (const float*)d_in[1];
    const float* values  = (const float*)d_in[2];
    // d_in[3] = pad_mask (unused by the reference, faithfully ignored)
    const float* WKb = (const float*)d_in[5];
    const float* WQb = (const float*)d_in[7];
    const float* WVb = (const float*)d_in[9];
    const float* WOb = (const float*)d_in[11];

    char* ws = (char*)d_ws;
    const size_t MB = 1 << 20;
    u16* Kbh = (u16*)(ws + 0 * MB);
    u16* Qbh = (u16*)(ws + 16 * MB);
    u16* Vtg = (u16*)(ws + 32 * MB);
    u16* Xk  = (u16*)(ws + 48 * MB);
    u16* Xq  = (u16*)(ws + 64 * MB);
    u16* Xv  = (u16*)(ws + 80 * MB);
    u16* Wk  = (u16*)(ws + 96 * MB);
    u16* Wq  = (u16*)(ws + 98 * MB);
    u16* Wv  = (u16*)(ws + 100 * MB);
    u16* Wo  = (u16*)(ws + 102 * MB);
    u16* ctx = (u16*)(ws + 48 * MB);   // aliases Xk (dead after QKV projection)

    cast_all<<<14336, 256, 0, stream>>>(keys, queries, values,
                                        (const float*)d_in[4], (const float*)d_in[6],
                                        (const float*)d_in[8], (const float*)d_in[10],
                                        Xk, Xq, Xv, Wk, Wq, Wv, Wo);

    const float kscale = 1.4426950408889634f * 0.125f;  // log2(e)/sqrt(d_key)
    gemm_qkv<<<1536, 256, 0, stream>>>(Xk, Xq, Xv, Wk, Wq, Wv,
                                       WKb, WQb, WVb, Kbh, Qbh, Vtg, kscale);

    attn_kernel<<<1024, 256, 0, stream>>>(Kbh, Qbh, Vtg, ctx);

    gemm_out<<<1024, 256, 0, stream>>>(ctx, Wo, WOb, (float*)d_out);
}

// Round 6
// 348.814 us; speedup vs baseline: 1.4567x; 1.4567x over previous
//
#include <hip/hip_runtime.h>

typedef unsigned short u16;
typedef unsigned int u32;
typedef __attribute__((ext_vector_type(8))) short short8;
typedef __attribute__((ext_vector_type(4))) float f32x4;

// ---------------- helpers ----------------
__device__ __forceinline__ u16 f2bf(float f) {
    unsigned int u = __float_as_uint(f);
    u += 0x7fffu + ((u >> 16) & 1u);   // round-to-nearest-even
    return (u16)(u >> 16);
}

__device__ __forceinline__ u32 pack_trunc(float a, float b) {
    return __builtin_amdgcn_perm(__float_as_uint(b), __float_as_uint(a), 0x07060302u);
}

// async global->LDS, 16B per lane. LDS dest = wave-uniform base + lane*16.
__device__ __forceinline__ void gload16(const u16* g, const u16* l) {
    __builtin_amdgcn_global_load_lds(
        (const __attribute__((address_space(1))) unsigned int*)g,
        (__attribute__((address_space(3))) unsigned int*)l, 16, 0, 0);
}

// ---------------- fused cast fp32 -> bf16 (all 7 tensors, one launch) ----------------
__global__ __launch_bounds__(256) void cast_all(const float* __restrict__ k,
                                                const float* __restrict__ q,
                                                const float* __restrict__ v,
                                                const float* __restrict__ wk,
                                                const float* __restrict__ wq,
                                                const float* __restrict__ wv,
                                                const float* __restrict__ wo,
                                                u16* __restrict__ Xk, u16* __restrict__ Xq,
                                                u16* __restrict__ Xv, u16* __restrict__ Wk,
                                                u16* __restrict__ Wq, u16* __restrict__ Wv,
                                                u16* __restrict__ Wo) {
    size_t i = ((size_t)blockIdx.x * 256 + threadIdx.x) * 8;
    const float* src; u16* dst; size_t off;
    if (i < 25165824) {                       // 3 x 2^23 activations
        int r = (int)(i >> 23); off = i & 8388607;
        src = r == 0 ? k : (r == 1 ? q : v);
        dst = r == 0 ? Xk : (r == 1 ? Xq : Xv);
    } else {                                  // 4 x 2^20 weights
        size_t j = i - 25165824;
        int r = (int)(j >> 20); off = j & 1048575;
        src = r == 0 ? wk : (r == 1 ? wq : (r == 2 ? wv : wo));
        dst = r == 0 ? Wk : (r == 1 ? Wq : (r == 2 ? Wv : Wo));
    }
    float4 a = *(const float4*)(src + off);
    float4 b = *(const float4*)(src + off + 4);
    union { u16 h[8]; uint4 u; } r8;
    r8.h[0] = f2bf(a.x); r8.h[1] = f2bf(a.y); r8.h[2] = f2bf(a.z); r8.h[3] = f2bf(a.w);
    r8.h[4] = f2bf(b.x); r8.h[5] = f2bf(b.y); r8.h[6] = f2bf(b.z); r8.h[7] = f2bf(b.w);
    *(uint4*)(dst + off) = r8.u;
}

// =====================================================================================
// GEMM core (R4, verified): 2-phase structure, BK=64, 128x128 tile, 4 waves.
// Bank swizzle: LDS row = 128B = 8 x 16B slots; LDS[r][slot] holds global[r][slot^(r&7)],
// staged by pre-permuting the global SOURCE column; reads use slot (kh*4+quad)^(l16&7).
// =====================================================================================

// ---------------- batched QKV GEMM, XCD-swizzled 1-D grid (1536 blocks) ----------------
__global__ __launch_bounds__(256) void gemm_qkv(const u16* __restrict__ Xk,
                                                const u16* __restrict__ Xq,
                                                const u16* __restrict__ Xv,
                                                const u16* __restrict__ Wk,
                                                const u16* __restrict__ Wq,
                                                const u16* __restrict__ Wv,
                                                const float* __restrict__ bK,
                                                const float* __restrict__ bQ,
                                                const float* __restrict__ bV,
                                                u16* __restrict__ Kbh,
                                                u16* __restrict__ Qbh,
                                                u16* __restrict__ Vtg,
                                                float kscale) {
    __shared__ u16 sA[128 * 64];
    __shared__ u16 sB[128 * 64];
    const int f = blockIdx.x;
    const int z = f >> 9;
    const int r9 = f & 511;
    const int i_idx = (r9 & 7) | (((r9 >> 6) & 7) << 3);
    const int j_idx = (r9 >> 3) & 7;

    const u16* X = z == 0 ? Xk : (z == 1 ? Xq : Xv);
    const u16* W = z == 0 ? Wk : (z == 1 ? Wq : Wv);
    const float* bias = z == 0 ? bK : (z == 1 ? bQ : bV);
    u16* out = z == 0 ? Kbh : (z == 1 ? Qbh : Vtg);
    const float scale = z == 0 ? kscale : 1.0f;

    const int tid  = threadIdx.x;
    const int wave = tid >> 6, lane = tid & 63;
    const int quad = lane >> 4, l16 = lane & 15;
    const int wm = wave & 1, wn = wave >> 1;
    const int i0 = i_idx * 128, j0 = j_idx * 128;

    const int r = tid >> 3;
    const int sg = (tid & 7) ^ (r & 7);
    const u16* gA = X + (size_t)(i0 + r) * 1024 + sg * 8;
    const u16* gB = W + (size_t)(j0 + r) * 1024 + sg * 8;
    u16* dA = sA + wave * 512;
    u16* dB = sB + wave * 512;
    const int sx = l16 & 7;   // read-side XOR

    f32x4 acc[4][4];
    #pragma unroll
    for (int mt = 0; mt < 4; mt++)
        #pragma unroll
        for (int nt = 0; nt < 4; nt++) acc[mt][nt] = (f32x4){0.f, 0.f, 0.f, 0.f};

    for (int kk = 0; kk < 1024; kk += 64) {
        __syncthreads();
        gload16(gA + kk,         dA);
        gload16(gA + kk + 32768, dA + 2048);
        gload16(gA + kk + 65536, dA + 4096);
        gload16(gA + kk + 98304, dA + 6144);
        gload16(gB + kk,         dB);
        gload16(gB + kk + 32768, dB + 2048);
        gload16(gB + kk + 65536, dB + 4096);
        gload16(gB + kk + 98304, dB + 6144);
        __syncthreads();
        short8 bf[4][2];
        #pragma unroll
        for (int nt = 0; nt < 4; nt++)
            #pragma unroll
            for (int kh = 0; kh < 2; kh++)
                bf[nt][kh] = *(const short8*)&sB[(wn * 64 + nt * 16 + l16) * 64 +
                                                 ((kh * 4 + quad) ^ sx) * 8];
        #pragma unroll
        for (int mt = 0; mt < 4; mt++) {
            const int arow = (wm * 64 + mt * 16 + l16) * 64;
            short8 a0 = *(const short8*)&sA[arow + ((quad) ^ sx) * 8];
            short8 a1 = *(const short8*)&sA[arow + ((4 + quad) ^ sx) * 8];
            #pragma unroll
            for (int nt = 0; nt < 4; nt++) {
                acc[mt][nt] = __builtin_amdgcn_mfma_f32_16x16x32_bf16(a0, bf[nt][0], acc[mt][nt], 0, 0, 0);
                acc[mt][nt] = __builtin_amdgcn_mfma_f32_16x16x32_bf16(a1, bf[nt][1], acc[mt][nt], 0, 0, 0);
            }
        }
    }

    #pragma unroll
    for (int mt = 0; mt < 4; mt++) {
        #pragma unroll
        for (int nt = 0; nt < 4; nt++) {
            int j = j0 + wn * 64 + nt * 16 + l16;
            float bj = bias[j];
            #pragma unroll
            for (int rr = 0; rr < 4; rr++) {
                int i = i0 + wm * 64 + mt * 16 + quad * 4 + rr;
                float v = (acc[mt][nt][rr] + bj) * scale;
                int b = i >> 11, t = i & 2047;
                int h = j >> 6,  dd = j & 63;
                size_t idx;
                if (z == 2) idx = (((size_t)(b * 16 + h)) * 64 + dd) * 2048 + t;
                else        idx = (((size_t)(b * 16 + h)) * 2048 + t) * 64 + dd;
                out[idx] = f2bf(v);
            }
        }
    }
}

// ---------------- output GEMM: 128x64 tile, XCD-swizzled (1024 blocks), BK=64 ---------
__global__ __launch_bounds__(256) void gemm_out(const u16* __restrict__ X,
                                                const u16* __restrict__ W,
                                                const float* __restrict__ bias,
                                                float* __restrict__ out) {
    __shared__ u16 sA[128 * 64];
    __shared__ u16 sB[64 * 64];
    const int f = blockIdx.x;
    const int j_idx = (f >> 3) & 15;
    const int i_idx = (f & 7) | ((f >> 7) << 3);
    const int tid  = threadIdx.x;
    const int wave = tid >> 6, lane = tid & 63;
    const int quad = lane >> 4, l16 = lane & 15;
    const int wm = wave & 1, wn = wave >> 1;
    const int i0 = i_idx * 128, j0 = j_idx * 64;

    const int r = tid >> 3;
    const int sg = (tid & 7) ^ (r & 7);
    const u16* gA = X + (size_t)(i0 + r) * 1024 + sg * 8;
    const u16* gB = W + (size_t)(j0 + r) * 1024 + sg * 8;
    u16* dA = sA + wave * 512;
    u16* dB = sB + wave * 512;
    const int sx = l16 & 7;

    f32x4 acc[4][2];
    #pragma unroll
    for (int mt = 0; mt < 4; mt++) {
        acc[mt][0] = (f32x4){0.f, 0.f, 0.f, 0.f};
        acc[mt][1] = (f32x4){0.f, 0.f, 0.f, 0.f};
    }

    for (int kk = 0; kk < 1024; kk += 64) {
        __syncthreads();
        gload16(gA + kk,         dA);
        gload16(gA + kk + 32768, dA + 2048);
        gload16(gA + kk + 65536, dA + 4096);
        gload16(gA + kk + 98304, dA + 6144);
        gload16(gB + kk,         dB);
        gload16(gB + kk + 32768, dB + 2048);
        __syncthreads();
        short8 bf[2][2];
        #pragma unroll
        for (int nt = 0; nt < 2; nt++)
            #pragma unroll
            for (int kh = 0; kh < 2; kh++)
                bf[nt][kh] = *(const short8*)&sB[(wn * 32 + nt * 16 + l16) * 64 +
                                                 ((kh * 4 + quad) ^ sx) * 8];
        #pragma unroll
        for (int mt = 0; mt < 4; mt++) {
            const int arow = (wm * 64 + mt * 16 + l16) * 64;
            short8 a0 = *(const short8*)&sA[arow + ((quad) ^ sx) * 8];
            short8 a1 = *(const short8*)&sA[arow + ((4 + quad) ^ sx) * 8];
            #pragma unroll
            for (int nt = 0; nt < 2; nt++) {
                acc[mt][nt] = __builtin_amdgcn_mfma_f32_16x16x32_bf16(a0, bf[nt][0], acc[mt][nt], 0, 0, 0);
                acc[mt][nt] = __builtin_amdgcn_mfma_f32_16x16x32_bf16(a1, bf[nt][1], acc[mt][nt], 0, 0, 0);
            }
        }
    }

    #pragma unroll
    for (int mt = 0; mt < 4; mt++) {
        #pragma unroll
        for (int nt = 0; nt < 2; nt++) {
            int j = j0 + wn * 32 + nt * 16 + l16;
            float bj = bias[j];
            #pragma unroll
            for (int rr = 0; rr < 4; rr++) {
                int i = i0 + wm * 64 + mt * 16 + quad * 4 + rr;
                out[(size_t)i * 1024 + j] = acc[mt][nt][rr] + bj;
            }
        }
    }
}

// ---------------- flash attention v6 (1024 blocks) ----------------
// v5 layout kept (128B rows + 16B-slot XOR swizzle; T-chunks=16; setprio).
// ONE change vs v5: __launch_bounds__(256, 2) instead of (256, 4). v5's (256,4)
// forced a 64-VGPR cap -> persistent state (bk/aq/av/accO ~110 regs) spilled to
// scratch every iteration (FETCH 568MB / WRITE 454MB = spill traffic, 3x slower).
// (256,2) lifts the cap; natural allocation ~100-120 <= 128 still allows 4 waves/SIMD
// occupancy with the 1024-block grid -- v5's occupancy goal without the spill.
__global__ __launch_bounds__(256, 2) void attn_kernel(const u16* __restrict__ Kbh,
                                                      const u16* __restrict__ Qbh,
                                                      const u16* __restrict__ Vtg,
                                                      u16* __restrict__ ctx) {
    __shared__ u16 sQ[64 * 64];              // [s_local][dk], swizzled slots
    __shared__ u16 sVt[64 * 64];             // [dk][s_local], swizzled slots
    __shared__ u16 sP[4 * 2 * 16 * 64];      // [wave][buf][t16][s64], swizzled 8B units
    const int f = blockIdx.x;
    const int bh = (f & 7) | ((f >> 7) << 3);
    const int tx = (f >> 3) & 15;
    const int tid  = threadIdx.x;
    const int wave = tid >> 6, lane = tid & 63;
    const int quad = lane >> 4, l16 = lane & 15;
    const int sx = l16 & 7;
    const int tw = tx * 128 + wave * 32;
    const size_t base = (size_t)bh * 2048 * 64;

    // K as B-fragments, 2 t-groups x 2 dk-chunks, held in regs
    short8 bk[2][2];
    #pragma unroll
    for (int g = 0; g < 2; g++) {
        const u16* kr = Kbh + base + (size_t)(tw + g * 16 + l16) * 64 + quad * 8;
        bk[g][0] = *(const short8*)kr;
        bk[g][1] = *(const short8*)(kr + 32);
    }
    const short8 ones = {0x3F80, 0x3F80, 0x3F80, 0x3F80, 0x3F80, 0x3F80, 0x3F80, 0x3F80};

    f32x4 accO[2][4];
    #pragma unroll
    for (int g = 0; g < 2; g++)
        #pragma unroll
        for (int dt = 0; dt < 4; dt++) accO[g][dt] = (f32x4){0.f, 0.f, 0.f, 0.f};
    f32x4 accL[2];
    accL[0] = (f32x4){0.f, 0.f, 0.f, 0.f};
    accL[1] = (f32x4){0.f, 0.f, 0.f, 0.f};

    const int srow = tid >> 2, seg = tid & 3;
    const int s7 = srow & 7;
    const int st0 = ((2 * seg)     ^ s7) * 8;   // swizzled 16B-slot offsets for staging
    const int st1 = ((2 * seg + 1) ^ s7) * 8;
    u16* sPw = sP + wave * 2048;

    for (int s0 = 0; s0 < 2048; s0 += 64) {
        __syncthreads();
        {   // stage Q chunk [s][dk], swizzled
            const uint4* gq = (const uint4*)(Qbh + base + (size_t)(s0 + srow) * 64 + seg * 16);
            uint4 q0 = gq[0], q1 = gq[1];
            *(uint4*)&sQ[srow * 64 + st0] = q0;
            *(uint4*)&sQ[srow * 64 + st1] = q1;
        }
        {   // stage V^T chunk [dk][s], swizzled
            const uint4* gv = (const uint4*)(Vtg + ((size_t)bh * 64 + srow) * 2048 + s0 + seg * 16);
            uint4 v0 = gv[0], v1 = gv[1];
            *(uint4*)&sVt[srow * 64 + st0] = v0;
            *(uint4*)&sVt[srow * 64 + st1] = v1;
        }
        __syncthreads();

        // cache Q A-frags and V^T A-frags once; reuse for both t-groups
        short8 aq[4][2], av[2][4];
        #pragma unroll
        for (int nt = 0; nt < 4; nt++)
            #pragma unroll
            for (int kh = 0; kh < 2; kh++)
                aq[nt][kh] = *(const short8*)&sQ[(nt * 16 + l16) * 64 +
                                                 ((kh * 4 + quad) ^ sx) * 8];
        #pragma unroll
        for (int kk = 0; kk < 2; kk++)
            #pragma unroll
            for (int dt = 0; dt < 4; dt++)
                av[kk][dt] = *(const short8*)&sVt[(dt * 16 + l16) * 64 +
                                                  ((kk * 4 + quad) ^ sx) * 8];

        #pragma unroll
        for (int g = 0; g < 2; g++) {
            // S^T[s][t] for this group: A = Q (cached), B = K (regs)
            f32x4 aS[4];
            __builtin_amdgcn_s_setprio(1);
            #pragma unroll
            for (int nt = 0; nt < 4; nt++) {
                f32x4 s = __builtin_amdgcn_mfma_f32_16x16x32_bf16(aq[nt][0], bk[g][0],
                            (f32x4){0.f, 0.f, 0.f, 0.f}, 0, 0, 0);
                aS[nt] = __builtin_amdgcn_mfma_f32_16x16x32_bf16(aq[nt][1], bk[g][1], s, 0, 0, 0);
            }
            __builtin_amdgcn_s_setprio(0);
            // P^T = 2^(S^T): raw v_exp_f32, truncate-pack to bf16, swizzled 8B units
            u16* pb = sPw + (g & 1) * 1024;
            #pragma unroll
            for (int nt = 0; nt < 4; nt++) {
                float p0 = __builtin_amdgcn_exp2f(aS[nt][0]);
                float p1 = __builtin_amdgcn_exp2f(aS[nt][1]);
                float p2 = __builtin_amdgcn_exp2f(aS[nt][2]);
                float p3 = __builtin_amdgcn_exp2f(aS[nt][3]);
                uint2 pk = { pack_trunc(p0, p1), pack_trunc(p2, p3) };
                *(uint2*)&pb[l16 * 64 + ((nt * 4 + quad) ^ (sx << 1)) * 4] = pk;
            }
            // O^T += V^T @ P^T ; L += ones @ P^T
            __builtin_amdgcn_s_setprio(1);
            #pragma unroll
            for (int kk = 0; kk < 2; kk++) {
                short8 bp = *(const short8*)&pb[l16 * 64 +
                                                ((kk * 8 + quad * 2) ^ (sx << 1)) * 4];
                accL[g] = __builtin_amdgcn_mfma_f32_16x16x32_bf16(ones, bp, accL[g], 0, 0, 0);
                #pragma unroll
                for (int dt = 0; dt < 4; dt++)
                    accO[g][dt] = __builtin_amdgcn_mfma_f32_16x16x32_bf16(av[kk][dt], bp, accO[g][dt], 0, 0, 0);
            }
            __builtin_amdgcn_s_setprio(0);
        }
    }

    // epilogue: lane holds col t = tw+g*16+l16, rows d = dt*16+quad*4+r
    const int b = bh >> 4, h = bh & 15;
    #pragma unroll
    for (int g = 0; g < 2; g++) {
        float inv = 1.f / accL[g][0];
        int t = tw + g * 16 + l16;
        u16* orow = ctx + ((size_t)(b * 2048 + t)) * 1024 + h * 64;
        #pragma unroll
        for (int dt = 0; dt < 4; dt++) {
            union { u16 h4[4]; uint2 u; } o;
            #pragma unroll
            for (int rr = 0; rr < 4; rr++) o.h4[rr] = f2bf(accO[g][dt][rr] * inv);
            *(uint2*)&orow[dt * 16 + quad * 4] = o.u;
        }
    }
}

// ---------------- launcher ----------------
extern "C" void kernel_launch(void* const* d_in, const int* in_sizes, int n_in,
                              void* d_out, int out_size, void* d_ws, size_t ws_size,
                              hipStream_t stream) {
    const float* keys    = (const float*)d_in[0];
    const float* queries = (const float*)d_in[1];
    const float* values  = (const float*)d_in[2];
    // d_in[3] = pad_mask (unused by the reference, faithfully ignored)
    const float* WKb = (const float*)d_in[5];
    const float* WQb = (const float*)d_in[7];
    const float* WVb = (const float*)d_in[9];
    const float* WOb = (const float*)d_in[11];

    char* ws = (char*)d_ws;
    const size_t MB = 1 << 20;
    u16* Kbh = (u16*)(ws + 0 * MB);
    u16* Qbh = (u16*)(ws + 16 * MB);
    u16* Vtg = (u16*)(ws + 32 * MB);
    u16* Xk  = (u16*)(ws + 48 * MB);
    u16* Xq  = (u16*)(ws + 64 * MB);
    u16* Xv  = (u16*)(ws + 80 * MB);
    u16* Wk  = (u16*)(ws + 96 * MB);
    u16* Wq  = (u16*)(ws + 98 * MB);
    u16* Wv  = (u16*)(ws + 100 * MB);
    u16* Wo  = (u16*)(ws + 102 * MB);
    u16* ctx = (u16*)(ws + 48 * MB);   // aliases Xk (dead after QKV projection)

    cast_all<<<14336, 256, 0, stream>>>(keys, queries, values,
                                        (const float*)d_in[4], (const float*)d_in[6],
                                        (const float*)d_in[8], (const float*)d_in[10],
                                        Xk, Xq, Xv, Wk, Wq, Wv, Wo);

    const float kscale = 1.4426950408889634f * 0.125f;  // log2(e)/sqrt(d_key)
    gemm_qkv<<<1536, 256, 0, stream>>>(Xk, Xq, Xv, Wk, Wq, Wv,
                                       WKb, WQb, WVb, Kbh, Qbh, Vtg, kscale);

    attn_kernel<<<1024, 256, 0, stream>>>(Kbh, Qbh, Vtg, ctx);

    gemm_out<<<1024, 256, 0, stream>>>(ctx, Wo, WOb, (float*)d_out);
}

// Round 7
// 326.439 us; speedup vs baseline: 1.5566x; 1.0685x over previous
//
#include <hip/hip_runtime.h>

typedef unsigned short u16;
typedef unsigned int u32;
typedef __attribute__((ext_vector_type(8))) short short8;
typedef __attribute__((ext_vector_type(4))) float f32x4;

// ---------------- helpers ----------------
__device__ __forceinline__ u16 f2bf(float f) {
    unsigned int u = __float_as_uint(f);
    u += 0x7fffu + ((u >> 16) & 1u);   // round-to-nearest-even
    return (u16)(u >> 16);
}

__device__ __forceinline__ u32 pack_trunc(float a, float b) {
    return __builtin_amdgcn_perm(__float_as_uint(b), __float_as_uint(a), 0x07060302u);
}

// async global->LDS, 16B per lane. LDS dest = wave-uniform base + lane*16.
__device__ __forceinline__ void gload16(const u16* g, const u16* l) {
    __builtin_amdgcn_global_load_lds(
        (const __attribute__((address_space(1))) unsigned int*)g,
        (__attribute__((address_space(3))) unsigned int*)l, 16, 0, 0);
}

// ---------------- fused cast fp32 -> bf16 (all 7 tensors, one launch) ----------------
__global__ __launch_bounds__(256) void cast_all(const float* __restrict__ k,
                                                const float* __restrict__ q,
                                                const float* __restrict__ v,
                                                const float* __restrict__ wk,
                                                const float* __restrict__ wq,
                                                const float* __restrict__ wv,
                                                const float* __restrict__ wo,
                                                u16* __restrict__ Xk, u16* __restrict__ Xq,
                                                u16* __restrict__ Xv, u16* __restrict__ Wk,
                                                u16* __restrict__ Wq, u16* __restrict__ Wv,
                                                u16* __restrict__ Wo) {
    size_t i = ((size_t)blockIdx.x * 256 + threadIdx.x) * 8;
    const float* src; u16* dst; size_t off;
    if (i < 25165824) {                       // 3 x 2^23 activations
        int r = (int)(i >> 23); off = i & 8388607;
        src = r == 0 ? k : (r == 1 ? q : v);
        dst = r == 0 ? Xk : (r == 1 ? Xq : Xv);
    } else {                                  // 4 x 2^20 weights
        size_t j = i - 25165824;
        int r = (int)(j >> 20); off = j & 1048575;
        src = r == 0 ? wk : (r == 1 ? wq : (r == 2 ? wv : wo));
        dst = r == 0 ? Wk : (r == 1 ? Wq : (r == 2 ? Wv : Wo));
    }
    float4 a = *(const float4*)(src + off);
    float4 b = *(const float4*)(src + off + 4);
    union { u16 h[8]; uint4 u; } r8;
    r8.h[0] = f2bf(a.x); r8.h[1] = f2bf(a.y); r8.h[2] = f2bf(a.z); r8.h[3] = f2bf(a.w);
    r8.h[4] = f2bf(b.x); r8.h[5] = f2bf(b.y); r8.h[6] = f2bf(b.z); r8.h[7] = f2bf(b.w);
    *(uint4*)(dst + off) = r8.u;
}

// =====================================================================================
// GEMM core (R4, verified): 2-phase structure, BK=64, 128x128 tile, 4 waves.
// Bank swizzle: LDS row = 128B = 8 x 16B slots; LDS[r][slot] holds global[r][slot^(r&7)],
// staged by pre-permuting the global SOURCE column; reads use slot (kh*4+quad)^(l16&7).
// =====================================================================================

// ---------------- batched QKV GEMM, XCD-swizzled 1-D grid (1536 blocks) ----------------
__global__ __launch_bounds__(256) void gemm_qkv(const u16* __restrict__ Xk,
                                                const u16* __restrict__ Xq,
                                                const u16* __restrict__ Xv,
                                                const u16* __restrict__ Wk,
                                                const u16* __restrict__ Wq,
                                                const u16* __restrict__ Wv,
                                                const float* __restrict__ bK,
                                                const float* __restrict__ bQ,
                                                const float* __restrict__ bV,
                                                u16* __restrict__ Kbh,
                                                u16* __restrict__ Qbh,
                                                u16* __restrict__ Vtg,
                                                float kscale) {
    __shared__ u16 sA[128 * 64];
    __shared__ u16 sB[128 * 64];
    const int f = blockIdx.x;
    const int z = f >> 9;
    const int r9 = f & 511;
    const int i_idx = (r9 & 7) | (((r9 >> 6) & 7) << 3);
    const int j_idx = (r9 >> 3) & 7;

    const u16* X = z == 0 ? Xk : (z == 1 ? Xq : Xv);
    const u16* W = z == 0 ? Wk : (z == 1 ? Wq : Wv);
    const float* bias = z == 0 ? bK : (z == 1 ? bQ : bV);
    u16* out = z == 0 ? Kbh : (z == 1 ? Qbh : Vtg);
    const float scale = z == 0 ? kscale : 1.0f;

    const int tid  = threadIdx.x;
    const int wave = tid >> 6, lane = tid & 63;
    const int quad = lane >> 4, l16 = lane & 15;
    const int wm = wave & 1, wn = wave >> 1;
    const int i0 = i_idx * 128, j0 = j_idx * 128;

    const int r = tid >> 3;
    const int sg = (tid & 7) ^ (r & 7);
    const u16* gA = X + (size_t)(i0 + r) * 1024 + sg * 8;
    const u16* gB = W + (size_t)(j0 + r) * 1024 + sg * 8;
    u16* dA = sA + wave * 512;
    u16* dB = sB + wave * 512;
    const int sx = l16 & 7;   // read-side XOR

    f32x4 acc[4][4];
    #pragma unroll
    for (int mt = 0; mt < 4; mt++)
        #pragma unroll
        for (int nt = 0; nt < 4; nt++) acc[mt][nt] = (f32x4){0.f, 0.f, 0.f, 0.f};

    for (int kk = 0; kk < 1024; kk += 64) {
        __syncthreads();
        gload16(gA + kk,         dA);
        gload16(gA + kk + 32768, dA + 2048);
        gload16(gA + kk + 65536, dA + 4096);
        gload16(gA + kk + 98304, dA + 6144);
        gload16(gB + kk,         dB);
        gload16(gB + kk + 32768, dB + 2048);
        gload16(gB + kk + 65536, dB + 4096);
        gload16(gB + kk + 98304, dB + 6144);
        __syncthreads();
        short8 bf[4][2];
        #pragma unroll
        for (int nt = 0; nt < 4; nt++)
            #pragma unroll
            for (int kh = 0; kh < 2; kh++)
                bf[nt][kh] = *(const short8*)&sB[(wn * 64 + nt * 16 + l16) * 64 +
                                                 ((kh * 4 + quad) ^ sx) * 8];
        #pragma unroll
        for (int mt = 0; mt < 4; mt++) {
            const int arow = (wm * 64 + mt * 16 + l16) * 64;
            short8 a0 = *(const short8*)&sA[arow + ((quad) ^ sx) * 8];
            short8 a1 = *(const short8*)&sA[arow + ((4 + quad) ^ sx) * 8];
            #pragma unroll
            for (int nt = 0; nt < 4; nt++) {
                acc[mt][nt] = __builtin_amdgcn_mfma_f32_16x16x32_bf16(a0, bf[nt][0], acc[mt][nt], 0, 0, 0);
                acc[mt][nt] = __builtin_amdgcn_mfma_f32_16x16x32_bf16(a1, bf[nt][1], acc[mt][nt], 0, 0, 0);
            }
        }
    }

    #pragma unroll
    for (int mt = 0; mt < 4; mt++) {
        #pragma unroll
        for (int nt = 0; nt < 4; nt++) {
            int j = j0 + wn * 64 + nt * 16 + l16;
            float bj = bias[j];
            #pragma unroll
            for (int rr = 0; rr < 4; rr++) {
                int i = i0 + wm * 64 + mt * 16 + quad * 4 + rr;
                float v = (acc[mt][nt][rr] + bj) * scale;
                int b = i >> 11, t = i & 2047;
                int h = j >> 6,  dd = j & 63;
                size_t idx;
                if (z == 2) idx = (((size_t)(b * 16 + h)) * 64 + dd) * 2048 + t;
                else        idx = (((size_t)(b * 16 + h)) * 2048 + t) * 64 + dd;
                out[idx] = f2bf(v);
            }
        }
    }
}

// ---------------- output GEMM: 128x64 tile, XCD-swizzled (1024 blocks), BK=64 ---------
__global__ __launch_bounds__(256) void gemm_out(const u16* __restrict__ X,
                                                const u16* __restrict__ W,
                                                const float* __restrict__ bias,
                                                float* __restrict__ out) {
    __shared__ u16 sA[128 * 64];
    __shared__ u16 sB[64 * 64];
    const int f = blockIdx.x;
    const int j_idx = (f >> 3) & 15;
    const int i_idx = (f & 7) | ((f >> 7) << 3);
    const int tid  = threadIdx.x;
    const int wave = tid >> 6, lane = tid & 63;
    const int quad = lane >> 4, l16 = lane & 15;
    const int wm = wave & 1, wn = wave >> 1;
    const int i0 = i_idx * 128, j0 = j_idx * 64;

    const int r = tid >> 3;
    const int sg = (tid & 7) ^ (r & 7);
    const u16* gA = X + (size_t)(i0 + r) * 1024 + sg * 8;
    const u16* gB = W + (size_t)(j0 + r) * 1024 + sg * 8;
    u16* dA = sA + wave * 512;
    u16* dB = sB + wave * 512;
    const int sx = l16 & 7;

    f32x4 acc[4][2];
    #pragma unroll
    for (int mt = 0; mt < 4; mt++) {
        acc[mt][0] = (f32x4){0.f, 0.f, 0.f, 0.f};
        acc[mt][1] = (f32x4){0.f, 0.f, 0.f, 0.f};
    }

    for (int kk = 0; kk < 1024; kk += 64) {
        __syncthreads();
        gload16(gA + kk,         dA);
        gload16(gA + kk + 32768, dA + 2048);
        gload16(gA + kk + 65536, dA + 4096);
        gload16(gA + kk + 98304, dA + 6144);
        gload16(gB + kk,         dB);
        gload16(gB + kk + 32768, dB + 2048);
        __syncthreads();
        short8 bf[2][2];
        #pragma unroll
        for (int nt = 0; nt < 2; nt++)
            #pragma unroll
            for (int kh = 0; kh < 2; kh++)
                bf[nt][kh] = *(const short8*)&sB[(wn * 32 + nt * 16 + l16) * 64 +
                                                 ((kh * 4 + quad) ^ sx) * 8];
        #pragma unroll
        for (int mt = 0; mt < 4; mt++) {
            const int arow = (wm * 64 + mt * 16 + l16) * 64;
            short8 a0 = *(const short8*)&sA[arow + ((quad) ^ sx) * 8];
            short8 a1 = *(const short8*)&sA[arow + ((4 + quad) ^ sx) * 8];
            #pragma unroll
            for (int nt = 0; nt < 2; nt++) {
                acc[mt][nt] = __builtin_amdgcn_mfma_f32_16x16x32_bf16(a0, bf[nt][0], acc[mt][nt], 0, 0, 0);
                acc[mt][nt] = __builtin_amdgcn_mfma_f32_16x16x32_bf16(a1, bf[nt][1], acc[mt][nt], 0, 0, 0);
            }
        }
    }

    #pragma unroll
    for (int mt = 0; mt < 4; mt++) {
        #pragma unroll
        for (int nt = 0; nt < 2; nt++) {
            int j = j0 + wn * 32 + nt * 16 + l16;
            float bj = bias[j];
            #pragma unroll
            for (int rr = 0; rr < 4; rr++) {
                int i = i0 + wm * 64 + mt * 16 + quad * 4 + rr;
                out[(size_t)i * 1024 + j] = acc[mt][nt][rr] + bj;
            }
        }
    }
}

// ---------------- flash attention v7 (512 blocks) ----------------
// R4 geometry (64 t-cols/wave, 72 MFMA/wave-iter -- best measured) + v6 swizzled LDS
// (128B rows, 16B-slot XOR: removed R4's 10.5M fragment-read conflicts) + T14
// async-STAGE split (issue next tile's Q/V global loads AFTER the LDS stores, BEFORE
// compute; loads land during the 72-MFMA phase instead of stalling the loop head).
// XCD swizzle: XCD = f&7; tx = (f>>3)&7; bh = (f&7)|((f>>6)<<3).
__global__ __launch_bounds__(256, 2) void attn_kernel(const u16* __restrict__ Kbh,
                                                      const u16* __restrict__ Qbh,
                                                      const u16* __restrict__ Vtg,
                                                      u16* __restrict__ ctx) {
    __shared__ u16 sQ[64 * 64];              // [s_local][dk], swizzled 16B slots
    __shared__ u16 sVt[64 * 64];             // [dk][s_local], swizzled 16B slots
    __shared__ u16 sP[4 * 2 * 16 * 64];      // [wave][buf][t16][s64], swizzled 8B units
    const int f = blockIdx.x;
    const int bh = (f & 7) | ((f >> 6) << 3);
    const int tx = (f >> 3) & 7;
    const int tid  = threadIdx.x;
    const int wave = tid >> 6, lane = tid & 63;
    const int quad = lane >> 4, l16 = lane & 15;
    const int sx = l16 & 7;
    const int tw = tx * 256 + wave * 64;
    const size_t base = (size_t)bh * 2048 * 64;

    // K as B-fragments, 4 t-groups x 2 dk-chunks, held in regs
    short8 bk[4][2];
    #pragma unroll
    for (int g = 0; g < 4; g++) {
        const u16* kr = Kbh + base + (size_t)(tw + g * 16 + l16) * 64 + quad * 8;
        bk[g][0] = *(const short8*)kr;
        bk[g][1] = *(const short8*)(kr + 32);
    }
    const short8 ones = {0x3F80, 0x3F80, 0x3F80, 0x3F80, 0x3F80, 0x3F80, 0x3F80, 0x3F80};

    f32x4 accO[4][4];
    #pragma unroll
    for (int g = 0; g < 4; g++)
        #pragma unroll
        for (int dt = 0; dt < 4; dt++) accO[g][dt] = (f32x4){0.f, 0.f, 0.f, 0.f};
    f32x4 accL[4];
    #pragma unroll
    for (int g = 0; g < 4; g++) accL[g] = (f32x4){0.f, 0.f, 0.f, 0.f};

    const int srow = tid >> 2, seg = tid & 3;
    const int s7 = srow & 7;
    const int st0 = ((2 * seg)     ^ s7) * 8;   // swizzled 16B-slot offsets for staging
    const int st1 = ((2 * seg + 1) ^ s7) * 8;
    u16* sPw = sP + wave * 2048;

    const u16* gQ = Qbh + base + (size_t)srow * 64 + seg * 16;
    const u16* gV = Vtg + ((size_t)bh * 64 + srow) * 2048 + seg * 16;

    // T14 prologue: load tile 0 into regs
    uint4 q0 = ((const uint4*)gQ)[0], q1 = ((const uint4*)gQ)[1];
    uint4 v0 = ((const uint4*)gV)[0], v1 = ((const uint4*)gV)[1];

    for (int s0 = 0; s0 < 2048; s0 += 64) {
        __syncthreads();
        // write-late: store the prefetched tile
        *(uint4*)&sQ[srow * 64 + st0]  = q0;
        *(uint4*)&sQ[srow * 64 + st1]  = q1;
        *(uint4*)&sVt[srow * 64 + st0] = v0;
        *(uint4*)&sVt[srow * 64 + st1] = v1;
        // issue-early: next tile's loads fly during the compute phase below
        if (s0 + 64 < 2048) {
            const uint4* nq = (const uint4*)(gQ + (size_t)(s0 + 64) * 64);
            const uint4* nv = (const uint4*)(gV + (s0 + 64));
            q0 = nq[0]; q1 = nq[1];
            v0 = nv[0]; v1 = nv[1];
        }
        __syncthreads();

        // cache Q A-frags and V^T A-frags once; reuse for all 4 t-groups
        short8 aq[4][2], av[2][4];
        #pragma unroll
        for (int nt = 0; nt < 4; nt++)
            #pragma unroll
            for (int kh = 0; kh < 2; kh++)
                aq[nt][kh] = *(const short8*)&sQ[(nt * 16 + l16) * 64 +
                                                 ((kh * 4 + quad) ^ sx) * 8];
        #pragma unroll
        for (int kk = 0; kk < 2; kk++)
            #pragma unroll
            for (int dt = 0; dt < 4; dt++)
                av[kk][dt] = *(const short8*)&sVt[(dt * 16 + l16) * 64 +
                                                  ((kk * 4 + quad) ^ sx) * 8];

        #pragma unroll
        for (int g = 0; g < 4; g++) {
            // S^T[s][t] for this group: A = Q (cached), B = K (regs)
            f32x4 aS[4];
            __builtin_amdgcn_s_setprio(1);
            #pragma unroll
            for (int nt = 0; nt < 4; nt++) {
                f32x4 s = __builtin_amdgcn_mfma_f32_16x16x32_bf16(aq[nt][0], bk[g][0],
                            (f32x4){0.f, 0.f, 0.f, 0.f}, 0, 0, 0);
                aS[nt] = __builtin_amdgcn_mfma_f32_16x16x32_bf16(aq[nt][1], bk[g][1], s, 0, 0, 0);
            }
            __builtin_amdgcn_s_setprio(0);
            // P^T = 2^(S^T): raw v_exp_f32, truncate-pack to bf16, swizzled 8B units
            u16* pb = sPw + (g & 1) * 1024;
            #pragma unroll
            for (int nt = 0; nt < 4; nt++) {
                float p0 = __builtin_amdgcn_exp2f(aS[nt][0]);
                float p1 = __builtin_amdgcn_exp2f(aS[nt][1]);
                float p2 = __builtin_amdgcn_exp2f(aS[nt][2]);
                float p3 = __builtin_amdgcn_exp2f(aS[nt][3]);
                uint2 pk = { pack_trunc(p0, p1), pack_trunc(p2, p3) };
                *(uint2*)&pb[l16 * 64 + ((nt * 4 + quad) ^ (sx << 1)) * 4] = pk;
            }
            // O^T += V^T @ P^T ; L += ones @ P^T
            __builtin_amdgcn_s_setprio(1);
            #pragma unroll
            for (int kk = 0; kk < 2; kk++) {
                short8 bp = *(const short8*)&pb[l16 * 64 +
                                                ((kk * 8 + quad * 2) ^ (sx << 1)) * 4];
                accL[g] = __builtin_amdgcn_mfma_f32_16x16x32_bf16(ones, bp, accL[g], 0, 0, 0);
                #pragma unroll
                for (int dt = 0; dt < 4; dt++)
                    accO[g][dt] = __builtin_amdgcn_mfma_f32_16x16x32_bf16(av[kk][dt], bp, accO[g][dt], 0, 0, 0);
            }
            __builtin_amdgcn_s_setprio(0);
        }
    }

    // epilogue: lane holds col t = tw+g*16+l16, rows d = dt*16+quad*4+r
    const int b = bh >> 4, h = bh & 15;
    #pragma unroll
    for (int g = 0; g < 4; g++) {
        float inv = 1.f / accL[g][0];
        int t = tw + g * 16 + l16;
        u16* orow = ctx + ((size_t)(b * 2048 + t)) * 1024 + h * 64;
        #pragma unroll
        for (int dt = 0; dt < 4; dt++) {
            union { u16 h4[4]; uint2 u; } o;
            #pragma unroll
            for (int rr = 0; rr < 4; rr++) o.h4[rr] = f2bf(accO[g][dt][rr] * inv);
            *(uint2*)&orow[dt * 16 + quad * 4] = o.u;
        }
    }
}

// ---------------- launcher ----------------
extern "C" void kernel_launch(void* const* d_in, const int* in_sizes, int n_in,
                              void* d_out, int out_size, void* d_ws, size_t ws_size,
                              hipStream_t stream) {
    const float* keys    = (const float*)d_in[0];
    const float* queries = (const float*)d_in[1];
    const float* values  = (const float*)d_in[2];
    // d_in[3] = pad_mask (unused by the reference, faithfully ignored)
    const float* WKb = (const float*)d_in[5];
    const float* WQb = (const float*)d_in[7];
    const float* WVb = (const float*)d_in[9];
    const float* WOb = (const float*)d_in[11];

    char* ws = (char*)d_ws;
    const size_t MB = 1 << 20;
    u16* Kbh = (u16*)(ws + 0 * MB);
    u16* Qbh = (u16*)(ws + 16 * MB);
    u16* Vtg = (u16*)(ws + 32 * MB);
    u16* Xk  = (u16*)(ws + 48 * MB);
    u16* Xq  = (u16*)(ws + 64 * MB);
    u16* Xv  = (u16*)(ws + 80 * MB);
    u16* Wk  = (u16*)(ws + 96 * MB);
    u16* Wq  = (u16*)(ws + 98 * MB);
    u16* Wv  = (u16*)(ws + 100 * MB);
    u16* Wo  = (u16*)(ws + 102 * MB);
    u16* ctx = (u16*)(ws + 48 * MB);   // aliases Xk (dead after QKV projection)

    cast_all<<<14336, 256, 0, stream>>>(keys, queries, values,
                                        (const float*)d_in[4], (const float*)d_in[6],
                                        (const float*)d_in[8], (const float*)d_in[10],
                                        Xk, Xq, Xv, Wk, Wq, Wv, Wo);

    const float kscale = 1.4426950408889634f * 0.125f;  // log2(e)/sqrt(d_key)
    gemm_qkv<<<1536, 256, 0, stream>>>(Xk, Xq, Xv, Wk, Wq, Wv,
                                       WKb, WQb, WVb, Kbh, Qbh, Vtg, kscale);

    attn_kernel<<<512, 256, 0, stream>>>(Kbh, Qbh, Vtg, ctx);

    gemm_out<<<1024, 256, 0, stream>>>(ctx, Wo, WOb, (float*)d_out);
}